// Round 11
// baseline (8151.810 us; speedup 1.0000x reference)
//
#include <hip/hip_runtime.h>

typedef _Float16 f16;
typedef _Float16 half8 __attribute__((ext_vector_type(8)));
typedef float f32x4 __attribute__((ext_vector_type(4)));
typedef unsigned u32x4 __attribute__((ext_vector_type(4)));
typedef unsigned u32x2 __attribute__((ext_vector_type(2)));

#define TT 512
#define HID 1024
#define VKEY 0x5AD00000u

__device__ __forceinline__ half8 cvt8(f32x4 lo, f32x4 hi) {
  half8 r;
  r[0]=(f16)lo[0]; r[1]=(f16)lo[1]; r[2]=(f16)lo[2]; r[3]=(f16)lo[3];
  r[4]=(f16)hi[0]; r[5]=(f16)hi[1]; r[6]=(f16)hi[2]; r[7]=(f16)hi[3];
  return r;
}
// device-scope coherent (write-through LLC / read past L2); never flush caches
__device__ __forceinline__ void st_sc32(unsigned* p, unsigned v) {
  asm volatile("global_store_dword %0, %1, off sc0 sc1" :: "v"(p), "v"(v) : "memory");
}
__device__ __forceinline__ void st_sc64(void* p, u32x2 v) {
  asm volatile("global_store_dwordx2 %0, %1, off sc0 sc1" :: "v"(p), "v"(v) : "memory");
}
__device__ __forceinline__ void st_sc128(void* p, u32x4 v) {
  asm volatile("global_store_dwordx4 %0, %1, off sc0 sc1" :: "v"(p), "v"(v) : "memory");
}
__device__ __forceinline__ unsigned ld_sc32(const unsigned* p) {
  unsigned v;
  asm volatile("global_load_dword %0, %1, off sc0 sc1\ns_waitcnt vmcnt(0)"
               : "=v"(v) : "v"(p) : "memory");
  return v;
}
__device__ __forceinline__ u32x4 ld_sc128_nw(const u32x4* p) {   // no internal wait
  u32x4 v;
  asm volatile("global_load_dwordx4 %0, %1, off sc0 sc1" : "=v"(v) : "v"(p) : "memory");
  return v;
}
__device__ __forceinline__ float sigm(float x)  { return 1.f/(1.f + __expf(-x)); }
__device__ __forceinline__ float ftanh(float x) { return 1.f - 2.f/(1.f + __expf(2.f*x)); }

// x [B][T][D] f32 -> xh [T][64 seg][64 b][16 c] f16 (WG-major; r9-verified layout)
__global__ void init_misc(const float* __restrict__ x, f16* __restrict__ xh) {
  size_t idx = (size_t)blockIdx.x*256 + threadIdx.x;
  size_t i = idx*8;
  int d = (int)(i & 1023);
  size_t bt = i >> 10;
  int t = (int)(bt & 511), b = (int)(bt >> 9);
  f32x4 a = *(const f32x4*)(x+i);
  f32x4 c4 = *(const f32x4*)(x+i+4);
  int s = d >> 4, c = d & 15;
  *(half8*)(xh + (((size_t)t*64 + s)*64 + b)*16 + c) = cvt8(a,c4);
}

// 256 WGs x 512 thr. WG=(layer=(bid&7)>>1 -> XCD pair, 16 cols). Per iter t:
// waves0-3: gate(t-1) [reduce PART -> h; ONE dwordx4 sc store per thread packs
//   {4xf16 hd, ver=VKEY|t} -> data+flag arrive atomically], then upstream fDown
//   poll, then gx GEMM(t).  waves4-7: gh GEMM(t) gated ONLY by cell versions
//   (plain-load fast path + sc-retry poll; version check defeats stale caches).
// 2 barriers/step. All GEMM/dump/reduce/layout formulas verbatim from r9 (proven).
__global__ __launch_bounds__(512, 2) void tsgru_k(
    const float* __restrict__ dtp, const float* __restrict__ Wih,
    const float* __restrict__ Whh, const float* __restrict__ bih,
    const float* __restrict__ bhh, const float* __restrict__ tau,
    const f16* __restrict__ xh, f16* __restrict__ H,
    u32x4* __restrict__ HDV, unsigned* __restrict__ fDown,
    float* __restrict__ out) {
  extern __shared__ char lds[];
  float* PART = (float*)lds;   // [24 slices][1088] f32 (col-major pad-68)

  const int tid = threadIdx.x, lane = tid & 63, wv = tid >> 6;
  const int g = wv >> 2, kh = wv & 3;
  const int bid = blockIdx.x;
  const int layer = (bid & 7) >> 1;                 // layer -> XCD pair
  const int wgl = (bid >> 3) | ((bid & 1) << 5);
  const int col0 = wgl * 16;
  const int rA = lane & 15, uA = lane >> 4;

  // ---- persistent weights (96 VGPR) — r9 verbatim
  const float* WL = (g ? Whh : Wih) + (size_t)layer*3072*HID;
  const int wcol = col0 + rA;
  half8 bW[3][8];
  #pragma unroll
  for (int q=0;q<3;q++)
    #pragma unroll
    for (int ks=0;ks<8;ks++) {
      const float* p = WL + (size_t)(q*HID + wcol)*HID + kh*256 + ks*32 + uA*8;
      bW[q][ks] = cvt8(*(const f32x4*)p, *(const f32x4*)(p+4));
    }

  // ---- gate constants (threads 0..255 = waves0-3), 4 cols/thread
  const int gb = tid >> 2, cg4 = (tid & 3) * 4;
  float bbR[4],bbZ[4],biN4[4],bhN4[4],ni[4],hdv[4];
  if (tid < 256) {
    #pragma unroll
    for (int e=0;e<4;e++) {
      const int col = col0 + cg4 + e;
      bbR[e]  = bih[layer*3072 + col]        + bhh[layer*3072 + col];
      bbZ[e]  = bih[layer*3072 + 1024 + col] + bhh[layer*3072 + 1024 + col];
      biN4[e] = bih[layer*3072 + 2048 + col];
      bhN4[e] = bhh[layer*3072 + 2048 + col];
      ni[e]   = -1.f/log1pf(expf(tau[layer*HID + col]));
      hdv[e]  = 0.f;
    }
  }

  // r9-verified A-fragment base (WG-major plane), and its cell-index form
  const int baseA = (kh*16 + (uA>>1))*1024 + rA*16 + (uA&1)*8;
  const int cb = baseA >> 2;                        // cells of 4 f16
  const f16* gxBase = (layer==0) ? xh : H + (size_t)(layer-1)*TT*65536;
  u32x4* HDVl = HDV + (size_t)layer*32*16384;       // 32-plane rotation of cells

  // gate: reduce PART + gates + stores for step tg
  auto doGate = [&](int tg, bool storeHd) {
    const float dtg = (tg < TT-1) ? dtp[gb*TT + tg + 1] : 0.f;
    float hv[4];
    #pragma unroll
    for (int e=0;e<4;e++) {
      const int pb = (cg4+e)*68 + gb;
      float SX0=0.f,SX1=0.f,SX2=0.f,SH0=0.f,SH1=0.f,SH2=0.f;
      #pragma unroll
      for (int w=0;w<4;w++) {
        const float* Px = PART + (size_t)(w*3)*1088 + pb;
        SX0 += Px[0]; SX1 += Px[1088]; SX2 += Px[2176];
        const float* Ph = PART + (size_t)((4+w)*3)*1088 + pb;
        SH0 += Ph[0]; SH1 += Ph[1088]; SH2 += Ph[2176];
      }
      const float r = sigm(SX0 + SH0 + bbR[e]);
      const float z = sigm(SX1 + SH1 + bbZ[e]);
      const float n = ftanh(SX2 + biN4[e] + r*(SH2 + bhN4[e]));
      hv[e] = (1.f - z)*n + z*hdv[e];
      hdv[e] = hv[e] * __expf(dtg * ni[e]);
    }
    if (layer < 3) {
      union { f16 h[4]; u32x2 u; } ph;
      #pragma unroll
      for (int e=0;e<4;e++) ph.h[e] = (f16)hv[e];
      st_sc64(H + ((size_t)layer*TT + tg)*65536 + (size_t)(wgl*64+gb)*16 + cg4, ph.u);
    } else {
      f32x4 ov; ov[0]=hv[0]; ov[1]=hv[1]; ov[2]=hv[2]; ov[3]=hv[3];
      *(f32x4*)(out + ((size_t)gb*TT + tg)*HID + col0 + cg4) = ov;
    }
    if (storeHd && tg < TT-1) {   // ONE dwordx4: {hd x4 f16, version, pad}
      union { f16 h[4]; u32x2 u; } pd;
      #pragma unroll
      for (int e=0;e<4;e++) pd.h[e] = (f16)hdv[e];
      u32x4 cell; cell[0]=pd.u[0]; cell[1]=pd.u[1];
      cell[2] = VKEY | (unsigned)(tg+1); cell[3] = 0u;
      st_sc128(HDVl + (size_t)((tg+1)&31)*16384 + (size_t)(wgl*64+gb)*4 + (tid&3), cell);
    }
  };

  for (int t = 0; t < TT; ++t) {
    f32x4 acc[4][3];
    #pragma unroll
    for (int m=0;m<4;m++) { acc[m][0]=(f32x4){0.f,0.f,0.f,0.f}; acc[m][1]=acc[m][0]; acc[m][2]=acc[m][0]; }

    if (g == 0) {
      // ======== waves0-3: gate(t-1) -> upstream poll -> gx GEMM(t) ========
      if (t > 0 && tid < 256) doGate(t-1, true);
      if (layer > 0) {
        const unsigned* fp = fDown + (((size_t)(layer-1)*TT + t)*64 + lane)*32;
        int gd = 0;
        while (__ballot(ld_sc32(fp) == 0u)) { __builtin_amdgcn_s_sleep(2); if (++gd > (1<<20)) break; }
      }
      const f16* P = gxBase + (size_t)t*65536;
      half8 aF[3][4];
      #pragma unroll
      for (int c=0;c<3;c++)
        #pragma unroll
        for (int m=0;m<4;m++)
          aF[c][m] = *(const half8*)(P + baseA + c*2048 + m*256);
      #pragma unroll
      for (int ks=0;ks<8;ks++) {
        #pragma unroll
        for (int m=0;m<4;m++) {
          const half8 a = aF[ks%3][m];
          acc[m][0] = __builtin_amdgcn_mfma_f32_16x16x32_f16(a, bW[0][ks], acc[m][0],0,0,0);
          acc[m][1] = __builtin_amdgcn_mfma_f32_16x16x32_f16(a, bW[1][ks], acc[m][1],0,0,0);
          acc[m][2] = __builtin_amdgcn_mfma_f32_16x16x32_f16(a, bW[2][ks], acc[m][2],0,0,0);
        }
        if (ks < 5) {
          #pragma unroll
          for (int m=0;m<4;m++)
            aF[(ks+3)%3][m] = *(const half8*)(P + baseA + (ks+3)*2048 + m*256);
        }
      }
      asm volatile("s_waitcnt vmcnt(0)" ::: "memory");   // gate stores + gx loads done
    } else if (t > 0) {
      // ======== waves4-7: gh GEMM(t) gated by cell versions ========
      const u32x4* Pc = HDVl + (size_t)(t & 31)*16384;
      const unsigned key = VKEY | (unsigned)t;
      u32x4 cw[2][4][2];
      #pragma unroll
      for (int par=0;par<2;par++)
        #pragma unroll
        for (int m=0;m<4;m++) {
          cw[par][m][0] = Pc[cb + par*512 + m*64];
          cw[par][m][1] = Pc[cb + par*512 + m*64 + 1];
        }
      #pragma unroll
      for (int ks=0;ks<8;ks++) {
        const int par = ks & 1;
        // verify versions; rare retry doubles as the poll (sc = fresh)
        int gd = 0;
        for (;;) {
          bool ok = true;
          #pragma unroll
          for (int m=0;m<4;m++)
            ok = ok && (cw[par][m][0][2] == key) && (cw[par][m][1][2] == key);
          if (__ballot(!ok) == 0ull) break;
          #pragma unroll
          for (int m=0;m<4;m++) {
            cw[par][m][0] = ld_sc128_nw(&Pc[cb + ks*512 + m*64]);
            cw[par][m][1] = ld_sc128_nw(&Pc[cb + ks*512 + m*64 + 1]);
          }
          asm volatile("s_waitcnt vmcnt(0)" ::: "memory");
          __builtin_amdgcn_sched_barrier(0);
          __builtin_amdgcn_s_sleep(1);
          if (++gd > (1<<19)) break;
        }
        #pragma unroll
        for (int m=0;m<4;m++) {
          union { unsigned w[4]; half8 h; } av;
          av.w[0]=cw[par][m][0][0]; av.w[1]=cw[par][m][0][1];
          av.w[2]=cw[par][m][1][0]; av.w[3]=cw[par][m][1][1];
          acc[m][0] = __builtin_amdgcn_mfma_f32_16x16x32_f16(av.h, bW[0][ks], acc[m][0],0,0,0);
          acc[m][1] = __builtin_amdgcn_mfma_f32_16x16x32_f16(av.h, bW[1][ks], acc[m][1],0,0,0);
          acc[m][2] = __builtin_amdgcn_mfma_f32_16x16x32_f16(av.h, bW[2][ks], acc[m][2],0,0,0);
        }
        if (ks < 6) {
          #pragma unroll
          for (int m=0;m<4;m++) {
            cw[par][m][0] = Pc[cb + (ks+2)*512 + m*64];
            cw[par][m][1] = Pc[cb + (ks+2)*512 + m*64 + 1];
          }
        }
      }
    }

    __builtin_amdgcn_s_barrier();                 // pre-dump (gate PART reads done)
    {
      float* Pb = PART + (size_t)(wv*3)*1088 + rA*68 + uA*4;
      #pragma unroll
      for (int q=0;q<3;q++)
        #pragma unroll
        for (int m=0;m<4;m++)
          *(f32x4*)(Pb + q*1088 + m*16) = acc[m][q];
    }
    asm volatile("s_waitcnt lgkmcnt(0)" ::: "memory");
    __builtin_amdgcn_s_barrier();                 // post-dump
    if (tid == 0 && t > 0 && layer < 3)           // H[t-1] drained before pre-dump bar
      st_sc32(fDown + (((size_t)layer*TT + (t-1))*64 + wgl)*32, 1u);
  }

  // ---- epilogue: gate(TT-1)
  if (tid < 256) doGate(TT-1, false);
  asm volatile("s_waitcnt vmcnt(0)" ::: "memory");
  __builtin_amdgcn_s_barrier();
  if (tid == 0 && layer < 3)
    st_sc32(fDown + (((size_t)layer*TT + (TT-1))*64 + wgl)*32, 1u);
}

extern "C" void kernel_launch(void* const* d_in, const int* in_sizes, int n_in,
                              void* d_out, int out_size, void* d_ws, size_t ws_size,
                              hipStream_t stream) {
  const float* x   = (const float*)d_in[0];
  const float* dtp = (const float*)d_in[1];
  const float* Wih = (const float*)d_in[2];
  const float* Whh = (const float*)d_in[3];
  const float* bih = (const float*)d_in[4];
  const float* bhh = (const float*)d_in[5];
  const float* tau = (const float*)d_in[6];
  float* out = (float*)d_out;
  char* ws = (char*)d_ws;

  // ws: xh 67,108,864 | H [3][512][65536]f16 201,326,592 | HDV [4][32][16384]x16B
  // 33,554,432 | fDown [4][512][64][32]u32 16,777,216  -> total 318,767,104 B
  f16* xh = (f16*)ws;
  f16* H  = (f16*)(ws + 67108864);
  u32x4* HDV = (u32x4*)(ws + 268435456);
  unsigned* fDown = (unsigned*)(ws + 268435456 + 33554432);

  (void)hipMemsetAsync(HDV, 0, 33554432, stream);    // versions invalid each launch
  (void)hipMemsetAsync(fDown, 0, 16777216, stream);
  init_misc<<<16384, 256, 0, stream>>>(x, xh);
  const int ldsBytes = 104448;                       // PART only; >80KB -> 1 WG/CU
  (void)hipFuncSetAttribute((const void*)tsgru_k, hipFuncAttributeMaxDynamicSharedMemorySize, ldsBytes);
  tsgru_k<<<256, 512, ldsBytes, stream>>>(dtp, Wih, Whh, bih, bhh, tau, xh, H, HDV, fDown, out);
}